// Round 2
// baseline (1132.697 us; speedup 1.0000x reference)
//
#include <hip/hip_runtime.h>
#include <stdint.h>

#define N_NODES 50000
#define N_EDGES 800000
#define HIDDEN  64
#define EDGE_F  32
#define CAT     160   // 2H + F
#define CAT2    128   // 2H

typedef __attribute__((ext_vector_type(8))) short          bf16x8;
typedef __attribute__((ext_vector_type(4))) float          f32x4;
typedef __attribute__((ext_vector_type(4))) unsigned short u16x4;
typedef __attribute__((ext_vector_type(2))) unsigned int   u32x2;

// RNE fp32 -> bf16 (prep kernel only; hot path uses v_cvt_pk_bf16_f32)
static __device__ __forceinline__ unsigned short f2bf(float f) {
  unsigned int u = __builtin_bit_cast(unsigned int, f);
  return (unsigned short)((u + 0x7fffu + ((u >> 16) & 1u)) >> 16);
}

// packed fp32x2 -> bf16x2 (RNE), 1 instruction
static __device__ __forceinline__ unsigned int cvt_pk_bf16(float a, float b) {
  unsigned int r;
  asm("v_cvt_pk_bf16_f32 %0, %1, %2" : "=v"(r) : "v"(a), "v"(b));
  return r;
}

// ---------------- prep: znode = z; zb = bf16(z); weights -> bf16 transposed ----
__global__ __launch_bounds__(256) void prep_kernel(
    const float* __restrict__ z, const float* __restrict__ Wffw,
    const float* __restrict__ Wf, const float* __restrict__ Ws,
    float* __restrict__ znode, unsigned short* __restrict__ zb,
    unsigned short* __restrict__ WtF,   // [160][160] (n-major, k-contig)
    unsigned short* __restrict__ Wfs) { // [128][128]; rows 0..63 = f, 64..127 = s
  int i = blockIdx.x * 256 + threadIdx.x;
  if (i < N_NODES * HIDDEN / 4) {
    f32x4 v = ((const f32x4*)z)[i];
    ((f32x4*)znode)[i] = v;
    u16x4 o = { f2bf(v[0]), f2bf(v[1]), f2bf(v[2]), f2bf(v[3]) };
    ((u16x4*)zb)[i] = o;
  }
  if (i < CAT * CAT) {
    int n = i / CAT, k = i % CAT;
    WtF[i] = f2bf(Wffw[k * CAT + n]);
  }
  if (i < CAT2 * CAT2) {
    int n = i / CAT2, k = i % CAT2;
    float v = (n < HIDDEN) ? Wf[k * HIDDEN + n] : Ws[k * HIDDEN + (n - HIDDEN)];
    Wfs[i] = f2bf(v);
  }
}

// ---------------- fused per-edge kernel: edge MLP GEMM + CGConv GEMM + scatter ----
// LDS (20480 B -> 8 blocks/CU = 32 waves):
//   Zs[64][128] bf16: 16B slots 0..7 = z_src, 8..15 = z_dst, XOR-swizzled
//     (physical slot p at row r holds logical slot (p&7)^(r&7) | (p&8)).
//     Staged by global_load_lds width=16 with lane-linear LDS dest; the swizzle
//     is applied by permuting the per-lane GLOBAL chunk (m173 pattern).
//   Ea[64][32] bf16: edge_attr, 16B slots XOR-swizzled by (row&3).
#define ZS_LD 128
#define EA_LD 32

__global__ __launch_bounds__(256, 8) void fused_edge_kernel(
    const unsigned short* __restrict__ zb, const float* __restrict__ ea,
    const int* __restrict__ ei,
    const unsigned short* __restrict__ WtF, const unsigned short* __restrict__ Wfs,
    const float* __restrict__ bffw, const float* __restrict__ bfv,
    const float* __restrict__ bsv,
    float* __restrict__ zedge, float* __restrict__ znode) {
  __shared__ __align__(16) unsigned short Zs[64 * ZS_LD]; // 16384 B
  __shared__ __align__(16) unsigned short Ea[64 * EA_LD]; //  4096 B
  const int tid = threadIdx.x;
  const int eb  = blockIdx.x * 64;

  // stage z rows: 64 edges x 16 chunks of 16B, direct global->LDS DMA.
  // LDS dest is lane-linear (tau*16B); read-side swizzle is pre-applied to the
  // global chunk index: cc' = cc ^ (el&7).
  #pragma unroll
  for (int i = 0; i < 4; ++i) {
    int tau  = tid + 256 * i;
    int el   = tau >> 4;
    int c    = tau & 15;
    int half = c >> 3;                 // 0 = src, 1 = dst
    int cc   = (c & 7) ^ (el & 7);     // pre-swizzled global chunk
    int node = ei[half * N_EDGES + eb + el];
    const unsigned short* src = &zb[node * HIDDEN + cc * 8];
    unsigned short* dst = &Zs[((tid & 0xC0) + i * 256) * 8]; // wave-uniform base
    __builtin_amdgcn_global_load_lds(
        (const __attribute__((address_space(1))) unsigned int*)src,
        (__attribute__((address_space(3))) unsigned int*)dst, 16, 0, 0);
  }
  // stage edge_attr (convert fp32->bf16 via cvt_pk): 64 edges x 8 chunks of 8B,
  // written at 16B-slot-swizzled column (slot ^= row&3).
  #pragma unroll
  for (int i = 0; i < 2; ++i) {
    int tau = tid + 256 * i;
    int el  = tau >> 3;
    int c   = tau & 7;
    f32x4 v = __builtin_nontemporal_load((const f32x4*)&ea[(eb + el) * EDGE_F + c * 4]);
    u32x2 o = { cvt_pk_bf16(v[0], v[1]), cvt_pk_bf16(v[2], v[3]) };
    int col = (c * 4) ^ ((el & 3) << 3);  // flips the 16B-slot bits only
    *(u32x2*)&Ea[el * EA_LD + col] = o;
  }
  __syncthreads();

  const int w    = tid >> 6;
  const int lane = tid & 63;
  const int ln   = lane & 15;
  const int q    = lane >> 4;
  const int mg   = w & 1;    // edge rows [mg*32, +32)
  const int nh   = w >> 1;   // edge-MLP col half [nh*80, +80); CG col half [nh*32, +32)
  const int xoZ  = (ln & 7) << 3;  // Zs read swizzle (shorts)
  const int xoE  = (ln & 3) << 3;  // Ea read swizzle (shorts)

  // ============ edge MLP: z_edge = relu(cat(src,dst,ea) @ Wffw + b) ============
  {
    f32x4 acc[5][2];
    #pragma unroll
    for (int t = 0; t < 5; ++t) {
      acc[t][0] = f32x4{0.f, 0.f, 0.f, 0.f};
      acc[t][1] = f32x4{0.f, 0.f, 0.f, 0.f};
    }
    #pragma unroll
    for (int ks = 0; ks < 5; ++ks) {
      bf16x8 a0, a1;
      if (ks < 4) {
        int off = (ks * 32 + q * 8) ^ xoZ;
        a0 = *(const bf16x8*)&Zs[(mg * 32 + ln) * ZS_LD + off];
        a1 = *(const bf16x8*)&Zs[(mg * 32 + 16 + ln) * ZS_LD + off];
      } else {
        int off = (q * 8) ^ xoE;
        a0 = *(const bf16x8*)&Ea[(mg * 32 + ln) * EA_LD + off];
        a1 = *(const bf16x8*)&Ea[(mg * 32 + 16 + ln) * EA_LD + off];
      }
      int k0 = ks * 32 + q * 8;
      #pragma unroll
      for (int t = 0; t < 5; ++t) {
        int n = nh * 80 + t * 16 + ln;
        bf16x8 b = *(const bf16x8*)&WtF[n * CAT + k0];
        acc[t][0] = __builtin_amdgcn_mfma_f32_16x16x32_bf16(a0, b, acc[t][0], 0, 0, 0);
        acc[t][1] = __builtin_amdgcn_mfma_f32_16x16x32_bf16(a1, b, acc[t][1], 0, 0, 0);
      }
    }
    #pragma unroll
    for (int t = 0; t < 5; ++t) {
      int n = nh * 80 + t * 16 + ln;
      float bias = bffw[n];
      #pragma unroll
      for (int ms = 0; ms < 2; ++ms) {
        #pragma unroll
        for (int r = 0; r < 4; ++r) {
          int m = mg * 32 + ms * 16 + q * 4 + r;
          float y = fmaxf(acc[t][ms][r] + bias, 0.0f);
          __builtin_nontemporal_store(y, &zedge[(eb + m) * CAT + n]);
        }
      }
    }
  }

  // ============ CGConv: msg = sig(cat(dst,src)@Wf+bf)*softplus(...Ws+bs) ======
  {
    f32x4 accF[2][2], accS[2][2];
    #pragma unroll
    for (int tt = 0; tt < 2; ++tt) {
      accF[tt][0] = f32x4{0.f, 0.f, 0.f, 0.f};
      accF[tt][1] = f32x4{0.f, 0.f, 0.f, 0.f};
      accS[tt][0] = f32x4{0.f, 0.f, 0.f, 0.f};
      accS[tt][1] = f32x4{0.f, 0.f, 0.f, 0.f};
    }
    // logical k = [dst(0..63) | src(64..127)]; physical Zs = [src | dst]
    const int cgoff[4] = {64, 96, 0, 32};
    #pragma unroll
    for (int ks = 0; ks < 4; ++ks) {
      int off = (cgoff[ks] + q * 8) ^ xoZ;
      bf16x8 a0 = *(const bf16x8*)&Zs[(mg * 32 + ln) * ZS_LD + off];
      bf16x8 a1 = *(const bf16x8*)&Zs[(mg * 32 + 16 + ln) * ZS_LD + off];
      int k0 = ks * 32 + q * 8;
      #pragma unroll
      for (int tt = 0; tt < 2; ++tt) {
        int n = nh * 32 + tt * 16 + ln;
        bf16x8 bF = *(const bf16x8*)&Wfs[n * CAT2 + k0];
        bf16x8 bS = *(const bf16x8*)&Wfs[(HIDDEN + n) * CAT2 + k0];
        accF[tt][0] = __builtin_amdgcn_mfma_f32_16x16x32_bf16(a0, bF, accF[tt][0], 0, 0, 0);
        accF[tt][1] = __builtin_amdgcn_mfma_f32_16x16x32_bf16(a1, bF, accF[tt][1], 0, 0, 0);
        accS[tt][0] = __builtin_amdgcn_mfma_f32_16x16x32_bf16(a0, bS, accS[tt][0], 0, 0, 0);
        accS[tt][1] = __builtin_amdgcn_mfma_f32_16x16x32_bf16(a1, bS, accS[tt][1], 0, 0, 0);
      }
    }
    int dc[2][4];
    #pragma unroll
    for (int ms = 0; ms < 2; ++ms)
      #pragma unroll
      for (int r = 0; r < 4; ++r)
        dc[ms][r] = ei[N_EDGES + eb + mg * 32 + ms * 16 + q * 4 + r];

    #pragma unroll
    for (int tt = 0; tt < 2; ++tt) {
      int h = nh * 32 + tt * 16 + ln;
      float bf_ = bfv[h];
      float bs_ = bsv[h];
      #pragma unroll
      for (int ms = 0; ms < 2; ++ms) {
        #pragma unroll
        for (int r = 0; r < 4; ++r) {
          float xf  = accF[tt][ms][r] + bf_;
          float xs  = accS[tt][ms][r] + bs_;
          // sigmoid: v_exp + v_rcp (no IEEE div sequence)
          float sig = __builtin_amdgcn_rcpf(1.0f + __expf(-xf));
          // softplus: fast v_exp/v_log path (no libm log1pf)
          float sp  = (xs > 20.0f) ? xs : __logf(1.0f + __expf(xs));
          atomicAdd(&znode[dc[ms][r] * HIDDEN + h], sig * sp);
        }
      }
    }
  }
}

extern "C" void kernel_launch(void* const* d_in, const int* in_sizes, int n_in,
                              void* d_out, int out_size, void* d_ws, size_t ws_size,
                              hipStream_t stream) {
  const float* z    = (const float*)d_in[0];
  const float* ea   = (const float*)d_in[1];
  const int*   ei   = (const int*)d_in[2];
  const float* Wffw = (const float*)d_in[3];
  const float* bffw = (const float*)d_in[4];
  const float* Wf   = (const float*)d_in[5];
  const float* bf_  = (const float*)d_in[6];
  const float* Ws   = (const float*)d_in[7];
  const float* bs_  = (const float*)d_in[8];

  float* znode = (float*)d_out;                       // [N_NODES, 64]
  float* zedge = znode + (size_t)N_NODES * HIDDEN;    // [N_EDGES, 160]

  unsigned short* zb  = (unsigned short*)d_ws;        // 50000*64 bf16 (6.4 MB)
  unsigned short* WtF = zb + (size_t)N_NODES * HIDDEN;
  unsigned short* Wfs = WtF + CAT * CAT;

  prep_kernel<<<(N_NODES * HIDDEN / 4 + 255) / 256, 256, 0, stream>>>(
      z, Wffw, Wf, Ws, znode, zb, WtF, Wfs);
  fused_edge_kernel<<<N_EDGES / 64, 256, 0, stream>>>(
      zb, ea, ei, WtF, Wfs, bffw, bf_, bs_, zedge, znode);
}

// Round 4
// 867.718 us; speedup vs baseline: 1.3054x; 1.3054x over previous
//
#include <hip/hip_runtime.h>
#include <stdint.h>

#define N_NODES 50000
#define N_EDGES 800000
#define HIDDEN  64
#define EDGE_F  32
#define CAT     160   // 2H + F
#define CAT2    128   // 2H

typedef __attribute__((ext_vector_type(8))) short          bf16x8;
typedef __attribute__((ext_vector_type(4))) float          f32x4;
typedef __attribute__((ext_vector_type(4))) unsigned short u16x4;
typedef __attribute__((ext_vector_type(2))) unsigned int   u32x2;

// RNE fp32 -> bf16 (prep kernel only; hot path uses v_cvt_pk_bf16_f32)
static __device__ __forceinline__ unsigned short f2bf(float f) {
  unsigned int u = __builtin_bit_cast(unsigned int, f);
  return (unsigned short)((u + 0x7fffu + ((u >> 16) & 1u)) >> 16);
}

// packed fp32x2 -> bf16x2 (RNE), 1 instruction
static __device__ __forceinline__ unsigned int cvt_pk_bf16(float a, float b) {
  unsigned int r;
  asm("v_cvt_pk_bf16_f32 %0, %1, %2" : "=v"(r) : "v"(a), "v"(b));
  return r;
}

// ---------------- prep: znode = z; zb = bf16(z); weights -> bf16 transposed ----
__global__ __launch_bounds__(256) void prep_kernel(
    const float* __restrict__ z, const float* __restrict__ Wffw,
    const float* __restrict__ Wf, const float* __restrict__ Ws,
    float* __restrict__ znode, unsigned short* __restrict__ zb,
    unsigned short* __restrict__ WtF,   // [160][160] (n-major, k-contig)
    unsigned short* __restrict__ Wfs) { // [128][128]; rows 0..63 = f, 64..127 = s
  int i = blockIdx.x * 256 + threadIdx.x;
  if (i < N_NODES * HIDDEN / 4) {
    f32x4 v = ((const f32x4*)z)[i];
    ((f32x4*)znode)[i] = v;
    u16x4 o = { f2bf(v[0]), f2bf(v[1]), f2bf(v[2]), f2bf(v[3]) };
    ((u16x4*)zb)[i] = o;
  }
  if (i < CAT * CAT) {
    int n = i / CAT, k = i % CAT;
    WtF[i] = f2bf(Wffw[k * CAT + n]);
  }
  if (i < CAT2 * CAT2) {
    int n = i / CAT2, k = i % CAT2;
    float v = (n < HIDDEN) ? Wf[k * HIDDEN + n] : Ws[k * HIDDEN + (n - HIDDEN)];
    Wfs[i] = f2bf(v);
  }
}

// ---------------- fused per-edge kernel: edge MLP GEMM + CGConv GEMM + scatter ----
// LDS usage: 30720 B total -> 5 blocks/CU (20 waves). The ZS_PAD is a
// deliberate concurrency throttle: at 8 blocks/CU (R2) the zb-gather working
// set + atomic lines thrashed L2/L3 (FETCH 122->389 MB, WRITE 794->1372 MB).
//   Zs[64][128] bf16: 16B slots 0..7 = z_src, 8..15 = z_dst, XOR-swizzled
//     (physical slot p at row r holds logical slot (p&7)^(r&7) | (p&8)).
//     Staged by global_load_lds width=16 with lane-linear LDS dest; the swizzle
//     is applied by permuting the per-lane GLOBAL chunk (m173 pattern).
//   Ea[64][32] bf16: edge_attr, 16B slots XOR-swizzled by (row&3).
#define ZS_LD 128
#define EA_LD 32
#define ZS_PAD 5120   // shorts; pads LDS block to 30720 B

__global__ __launch_bounds__(256, 5) void fused_edge_kernel(
    const unsigned short* __restrict__ zb, const float* __restrict__ ea,
    const int* __restrict__ ei,
    const unsigned short* __restrict__ WtF, const unsigned short* __restrict__ Wfs,
    const float* __restrict__ bffw, const float* __restrict__ bfv,
    const float* __restrict__ bsv,
    float* __restrict__ zedge, float* __restrict__ znode) {
  __shared__ __align__(16) unsigned short Zs[64 * ZS_LD + ZS_PAD]; // 26624 B
  __shared__ __align__(16) unsigned short Ea[64 * EA_LD];          //  4096 B
  const int tid = threadIdx.x;
  const int eb  = blockIdx.x * 64;

  // stage z rows: 64 edges x 16 chunks of 16B, direct global->LDS DMA.
  // LDS dest is lane-linear (tau*16B); read-side swizzle is pre-applied to the
  // global chunk index: cc' = cc ^ (el&7).
  #pragma unroll
  for (int i = 0; i < 4; ++i) {
    int tau  = tid + 256 * i;
    int el   = tau >> 4;
    int c    = tau & 15;
    int half = c >> 3;                 // 0 = src, 1 = dst
    int cc   = (c & 7) ^ (el & 7);     // pre-swizzled global chunk
    int node = ei[half * N_EDGES + eb + el];
    const unsigned short* src = &zb[node * HIDDEN + cc * 8];
    unsigned short* dst = &Zs[((tid & 0xC0) + i * 256) * 8]; // wave-uniform base
    __builtin_amdgcn_global_load_lds(
        (const __attribute__((address_space(1))) unsigned int*)src,
        (__attribute__((address_space(3))) unsigned int*)dst, 16, 0, 0);
  }
  // stage edge_attr (convert fp32->bf16 via cvt_pk): 64 edges x 8 chunks of 8B,
  // written at 16B-slot-swizzled column (slot ^= row&3).
  #pragma unroll
  for (int i = 0; i < 2; ++i) {
    int tau = tid + 256 * i;
    int el  = tau >> 3;
    int c   = tau & 7;
    f32x4 v = __builtin_nontemporal_load((const f32x4*)&ea[(eb + el) * EDGE_F + c * 4]);
    u32x2 o = { cvt_pk_bf16(v[0], v[1]), cvt_pk_bf16(v[2], v[3]) };
    int col = (c * 4) ^ ((el & 3) << 3);  // flips the 16B-slot bits only
    *(u32x2*)&Ea[el * EA_LD + col] = o;
  }
  __syncthreads();

  const int w    = tid >> 6;
  const int lane = tid & 63;
  const int ln   = lane & 15;
  const int q    = lane >> 4;
  const int mg   = w & 1;    // edge rows [mg*32, +32)
  const int nh   = w >> 1;   // edge-MLP col half [nh*80, +80); CG col half [nh*32, +32)
  const int xoZ  = (ln & 7) << 3;  // Zs read swizzle (shorts)
  const int xoE  = (ln & 3) << 3;  // Ea read swizzle (shorts)

  // ============ edge MLP: z_edge = relu(cat(src,dst,ea) @ Wffw + b) ============
  {
    f32x4 acc[5][2];
    #pragma unroll
    for (int t = 0; t < 5; ++t) {
      acc[t][0] = f32x4{0.f, 0.f, 0.f, 0.f};
      acc[t][1] = f32x4{0.f, 0.f, 0.f, 0.f};
    }
    #pragma unroll
    for (int ks = 0; ks < 5; ++ks) {
      bf16x8 a0, a1;
      if (ks < 4) {
        int off = (ks * 32 + q * 8) ^ xoZ;
        a0 = *(const bf16x8*)&Zs[(mg * 32 + ln) * ZS_LD + off];
        a1 = *(const bf16x8*)&Zs[(mg * 32 + 16 + ln) * ZS_LD + off];
      } else {
        int off = (q * 8) ^ xoE;
        a0 = *(const bf16x8*)&Ea[(mg * 32 + ln) * EA_LD + off];
        a1 = *(const bf16x8*)&Ea[(mg * 32 + 16 + ln) * EA_LD + off];
      }
      int k0 = ks * 32 + q * 8;
      #pragma unroll
      for (int t = 0; t < 5; ++t) {
        int n = nh * 80 + t * 16 + ln;
        bf16x8 b = *(const bf16x8*)&WtF[n * CAT + k0];
        acc[t][0] = __builtin_amdgcn_mfma_f32_16x16x32_bf16(a0, b, acc[t][0], 0, 0, 0);
        acc[t][1] = __builtin_amdgcn_mfma_f32_16x16x32_bf16(a1, b, acc[t][1], 0, 0, 0);
      }
    }
    #pragma unroll
    for (int t = 0; t < 5; ++t) {
      int n = nh * 80 + t * 16 + ln;
      float bias = bffw[n];
      #pragma unroll
      for (int ms = 0; ms < 2; ++ms) {
        #pragma unroll
        for (int r = 0; r < 4; ++r) {
          int m = mg * 32 + ms * 16 + q * 4 + r;
          float y = fmaxf(acc[t][ms][r] + bias, 0.0f);
          __builtin_nontemporal_store(y, &zedge[(eb + m) * CAT + n]);
        }
      }
    }
  }

  // ============ CGConv: msg = sig(cat(dst,src)@Wf+bf)*softplus(...Ws+bs) ======
  {
    f32x4 accF[2][2], accS[2][2];
    #pragma unroll
    for (int tt = 0; tt < 2; ++tt) {
      accF[tt][0] = f32x4{0.f, 0.f, 0.f, 0.f};
      accF[tt][1] = f32x4{0.f, 0.f, 0.f, 0.f};
      accS[tt][0] = f32x4{0.f, 0.f, 0.f, 0.f};
      accS[tt][1] = f32x4{0.f, 0.f, 0.f, 0.f};
    }
    // logical k = [dst(0..63) | src(64..127)]; physical Zs = [src | dst]
    const int cgoff[4] = {64, 96, 0, 32};
    #pragma unroll
    for (int ks = 0; ks < 4; ++ks) {
      int off = (cgoff[ks] + q * 8) ^ xoZ;
      bf16x8 a0 = *(const bf16x8*)&Zs[(mg * 32 + ln) * ZS_LD + off];
      bf16x8 a1 = *(const bf16x8*)&Zs[(mg * 32 + 16 + ln) * ZS_LD + off];
      int k0 = ks * 32 + q * 8;
      #pragma unroll
      for (int tt = 0; tt < 2; ++tt) {
        int n = nh * 32 + tt * 16 + ln;
        bf16x8 bF = *(const bf16x8*)&Wfs[n * CAT2 + k0];
        bf16x8 bS = *(const bf16x8*)&Wfs[(HIDDEN + n) * CAT2 + k0];
        accF[tt][0] = __builtin_amdgcn_mfma_f32_16x16x32_bf16(a0, bF, accF[tt][0], 0, 0, 0);
        accF[tt][1] = __builtin_amdgcn_mfma_f32_16x16x32_bf16(a1, bF, accF[tt][1], 0, 0, 0);
        accS[tt][0] = __builtin_amdgcn_mfma_f32_16x16x32_bf16(a0, bS, accS[tt][0], 0, 0, 0);
        accS[tt][1] = __builtin_amdgcn_mfma_f32_16x16x32_bf16(a1, bS, accS[tt][1], 0, 0, 0);
      }
    }
    int dc[2][4];
    #pragma unroll
    for (int ms = 0; ms < 2; ++ms)
      #pragma unroll
      for (int r = 0; r < 4; ++r)
        dc[ms][r] = ei[N_EDGES + eb + mg * 32 + ms * 16 + q * 4 + r];

    #pragma unroll
    for (int tt = 0; tt < 2; ++tt) {
      int h = nh * 32 + tt * 16 + ln;
      float bf_ = bfv[h];
      float bs_ = bsv[h];
      #pragma unroll
      for (int ms = 0; ms < 2; ++ms) {
        #pragma unroll
        for (int r = 0; r < 4; ++r) {
          float xf  = accF[tt][ms][r] + bf_;
          float xs  = accS[tt][ms][r] + bs_;
          // sigmoid: v_exp + v_rcp (no IEEE div sequence)
          float sig = __builtin_amdgcn_rcpf(1.0f + __expf(-xf));
          // softplus: fast v_exp/v_log path (no libm log1pf)
          float sp  = (xs > 20.0f) ? xs : __logf(1.0f + __expf(xs));
          atomicAdd(&znode[dc[ms][r] * HIDDEN + h], sig * sp);
        }
      }
    }
  }
}

extern "C" void kernel_launch(void* const* d_in, const int* in_sizes, int n_in,
                              void* d_out, int out_size, void* d_ws, size_t ws_size,
                              hipStream_t stream) {
  const float* z    = (const float*)d_in[0];
  const float* ea   = (const float*)d_in[1];
  const int*   ei   = (const int*)d_in[2];
  const float* Wffw = (const float*)d_in[3];
  const float* bffw = (const float*)d_in[4];
  const float* Wf   = (const float*)d_in[5];
  const float* bf_  = (const float*)d_in[6];
  const float* Ws   = (const float*)d_in[7];
  const float* bs_  = (const float*)d_in[8];

  float* znode = (float*)d_out;                       // [N_NODES, 64]
  float* zedge = znode + (size_t)N_NODES * HIDDEN;    // [N_EDGES, 160]

  unsigned short* zb  = (unsigned short*)d_ws;        // 50000*64 bf16 (6.4 MB)
  unsigned short* WtF = zb + (size_t)N_NODES * HIDDEN;
  unsigned short* Wfs = WtF + CAT * CAT;

  prep_kernel<<<(N_NODES * HIDDEN / 4 + 255) / 256, 256, 0, stream>>>(
      z, Wffw, Wf, Ws, znode, zb, WtF, Wfs);
  fused_edge_kernel<<<N_EDGES / 64, 256, 0, stream>>>(
      zb, ea, ei, WtF, Wfs, bffw, bf_, bs_, zedge, znode);
}